// Round 2
// baseline (238.144 us; speedup 1.0000x reference)
//
#include <hip/hip_runtime.h>

#define NB_BS   2048
#define NB_NINP 512
#define NB_NHID 512
#define NB_K    16
#define NB_T    8
#define NB_M    32
#define NB_C    768   // T * 3 * M
#define H_OUT_ELEMS (NB_BS * NB_NHID)   // 1048576

// ---------------------------------------------------------------------------
// Kernel 1: gi'[b][c] = sum_i x[b][i]*Wih[c][i] + bih[c] + (gate<2 ? bhh[c] : 0)
// 64x96 tile, BK=32, 256 threads, 4x6 micro-tile. Grid = 32x8 = 256 blocks
// (exactly 1/CU, perfectly balanced). bhh for r,z gates folded here so k2's
// epilogue only needs bhh_n.
// ---------------------------------------------------------------------------
__global__ __launch_bounds__(256)
void k1_gemm_gi(const float* __restrict__ x, const float* __restrict__ Wih,
                const float* __restrict__ bih, const float* __restrict__ bhh,
                float* __restrict__ gi)
{
    __shared__ __align__(16) float As[32][68];    // [k][row]
    __shared__ __align__(16) float Bs[32][100];   // [k][col]

    const int tid  = threadIdx.x;
    const int row0 = blockIdx.x * 64;
    const int col0 = blockIdx.y * 96;
    const int lrow = tid >> 2;            // 0..63
    const int lk   = (tid & 3) * 8;       // 0,8,16,24
    const int tr   = tid >> 4;            // 0..15 -> rows tr*4..
    const int tc   = tid & 15;            // 0..15 -> cols tc*6..

    const int c0 = tid >> 3,          kq0 = (tid & 7) * 4;
    const int c1 = (tid + 256) >> 3,  kq1 = ((tid + 256) & 7) * 4;
    const int c2 = (tid + 512) >> 3,  kq2 = ((tid + 512) & 7) * 4;

    const float* xp = x + (size_t)(row0 + lrow) * NB_NINP + lk;
    float4 a0 = *(const float4*)xp;
    float4 a1 = *(const float4*)(xp + 4);
    float4 b0 = *(const float4*)&Wih[(size_t)(col0 + c0) * NB_NINP + kq0];
    float4 b1 = *(const float4*)&Wih[(size_t)(col0 + c1) * NB_NINP + kq1];
    float4 b2 = *(const float4*)&Wih[(size_t)(col0 + c2) * NB_NINP + kq2];

    float acc[4][6];
    #pragma unroll
    for (int i = 0; i < 4; ++i)
        #pragma unroll
        for (int e = 0; e < 6; ++e) acc[i][e] = 0.f;

    for (int kb = 0; kb < NB_NINP; kb += 32) {
        __syncthreads();
        As[lk+0][lrow]=a0.x; As[lk+1][lrow]=a0.y; As[lk+2][lrow]=a0.z; As[lk+3][lrow]=a0.w;
        As[lk+4][lrow]=a1.x; As[lk+5][lrow]=a1.y; As[lk+6][lrow]=a1.z; As[lk+7][lrow]=a1.w;
        Bs[kq0+0][c0]=b0.x; Bs[kq0+1][c0]=b0.y; Bs[kq0+2][c0]=b0.z; Bs[kq0+3][c0]=b0.w;
        Bs[kq1+0][c1]=b1.x; Bs[kq1+1][c1]=b1.y; Bs[kq1+2][c1]=b1.z; Bs[kq1+3][c1]=b1.w;
        Bs[kq2+0][c2]=b2.x; Bs[kq2+1][c2]=b2.y; Bs[kq2+2][c2]=b2.z; Bs[kq2+3][c2]=b2.w;
        __syncthreads();
        if (kb + 32 < NB_NINP) {    // prefetch next K-slab into regs
            a0 = *(const float4*)(xp + kb + 32);
            a1 = *(const float4*)(xp + kb + 36);
            b0 = *(const float4*)&Wih[(size_t)(col0 + c0) * NB_NINP + kb + 32 + kq0];
            b1 = *(const float4*)&Wih[(size_t)(col0 + c1) * NB_NINP + kb + 32 + kq1];
            b2 = *(const float4*)&Wih[(size_t)(col0 + c2) * NB_NINP + kb + 32 + kq2];
        }
        #pragma unroll
        for (int kk = 0; kk < 32; ++kk) {
            const float4 av = *(const float4*)&As[kk][tr * 4];
            const float2 w0 = *(const float2*)&Bs[kk][tc * 6];
            const float2 w1 = *(const float2*)&Bs[kk][tc * 6 + 2];
            const float2 w2 = *(const float2*)&Bs[kk][tc * 6 + 4];
            const float avv[4] = {av.x, av.y, av.z, av.w};
            const float wvv[6] = {w0.x, w0.y, w1.x, w1.y, w2.x, w2.y};
            #pragma unroll
            for (int i = 0; i < 4; ++i)
                #pragma unroll
                for (int e = 0; e < 6; ++e)
                    acc[i][e] = fmaf(avv[i], wvv[e], acc[i][e]);
        }
    }

    float bias[6];
    #pragma unroll
    for (int e = 0; e < 6; ++e) {
        const int cl = tc * 6 + e;        // == c % 96 since col0 % 96 == 0
        const int c  = col0 + cl;
        bias[e] = bih[c] + (cl < 64 ? bhh[c] : 0.f);
    }
    #pragma unroll
    for (int i = 0; i < 4; ++i) {
        const size_t base = (size_t)(row0 + tr * 4 + i) * NB_C + col0 + tc * 6;
        #pragma unroll
        for (int e = 0; e < 6; ++e) gi[base + e] = acc[i][e] + bias[e];
    }
}

// ---------------------------------------------------------------------------
// Kernel 2: fused gh-GEMM + GRU gates + write-key logits + gumbel-argmax +
// gather. 256 blocks x 1024 threads (16 waves -> 4 waves/SIMD, 2x round-1
// occupancy). Block owns 8 b's; each b is split across 2 waves (kh = 8 k's
// each); each wave runs 2 passes of 4 k's with acc[4][12] to keep VGPR<=128.
// W_hh staged as 3 float4 planes P[q][mm][lane] -> 3 conflict-free
// ds_read_b128 per contraction step. h staged transposed HT[m][k] -> the 4
// h-broadcast values are one aligned b128. h_read hoisted; write-key dot (ww)
// precomputed per pass (no per-k shfl broadcast of h_read).
// ---------------------------------------------------------------------------
__global__ __launch_bounds__(1024)
void k2_fused(const float* __restrict__ h,      const float* __restrict__ Whh,
              const float* __restrict__ bhh,    const float* __restrict__ wread,
              const float* __restrict__ wwrite, const float* __restrict__ gumb,
              const float* __restrict__ gi,     float* __restrict__ out)
{
    __shared__ __align__(16) float4 P[3][32][64];   // 98304 B  W_hh planes
    __shared__ float WWT[NB_T * 16 * 32];           // 16384 B  [t][f][m]
    __shared__ float WR[512];                       //  2048 B  [m][f]
    __shared__ __align__(16) float HT[8][32][20];   // 20480 B  [bl][m][k]
    __shared__ __align__(16) float HR2[8][16][20];  // 10240 B  [bl][k][f]

    const int tid  = threadIdx.x;
    const int wave = tid >> 6, lane = tid & 63;
    const int bl   = wave >> 1, kh = wave & 1;
    const int b    = blockIdx.x * 8 + bl;
    const int m_   = lane & 31, half = lane >> 5;

    // ---- stage W_hh into planes: value for (lane, j=p*3+gc) at contraction mm
    float* PF = (float*)P;
    for (int i = tid; i < 24576; i += 1024) {       // Whh flat [c][m]; c=t*96+gc*32+mout
        const int c = i >> 5, mm = i & 31;
        const int t = c / 96, rem = c - t * 96;
        const int gc = rem >> 5, mout = rem & 31;
        const int j  = (t >> 1) * 3 + gc;
        const int sl = (t & 1) * 32 + mout;         // == reading lane
        PF[(((j >> 2) * 32 + mm) * 64 + sl) * 4 + (j & 3)] = Whh[i];
    }
    for (int i = tid; i < 4096; i += 1024) {        // wwrite flat [t][m][f]
        const int t = i >> 9, mo = (i >> 4) & 31, f = i & 15;
        WWT[t * 512 + f * 32 + mo] = wwrite[i];
    }
    if (tid < 512) WR[tid] = wread[tid];
    #pragma unroll
    for (int e = 0; e < 4; ++e) {                   // this wave's h half-row, transposed
        const int idx = kh * 256 + e * 64 + lane;
        HT[bl][idx & 31][idx >> 5] = h[(size_t)b * NB_NHID + idx];
    }
    __syncthreads();

    // ---- h_read for this wave's 8 k's: lane owns (k, f-pair)
    {
        const int kq = kh * 8 + (lane >> 3);
        const int f0 = (lane & 7) * 2;
        float s0 = 0.f, s1 = 0.f;
        #pragma unroll
        for (int mm = 0; mm < 32; ++mm) {
            const float hv = HT[bl][mm][kq];
            s0 = fmaf(hv, WR[mm * 16 + f0], s0);
            s1 = fmaf(hv, WR[mm * 16 + f0 + 1], s1);
        }
        HR2[bl][kq][f0]     = s0;
        HR2[bl][kq][f0 + 1] = s1;
    }

    // ---- per-lane gi' (bih + bhh_{r,z} already folded by k1) and bhh_n
    float gi_r[4][3], bhn[4];
    #pragma unroll
    for (int p = 0; p < 4; ++p) {
        const int t = 2 * p + half;
        #pragma unroll
        for (int gc = 0; gc < 3; ++gc)
            gi_r[p][gc] = gi[(size_t)b * NB_C + t * 96 + gc * 32 + m_];
        bhn[p] = bhh[t * 96 + 64 + m_];
    }

    #pragma unroll 1
    for (int pass = 0; pass < 2; ++pass) {
        const int k0 = kh * 8 + pass * 4;

        // ---- gh GEMM for 4 k's: 48 FMA per mm, 4 conflict-free b128 reads
        float acc[4][12];
        #pragma unroll
        for (int r = 0; r < 4; ++r)
            #pragma unroll
            for (int j = 0; j < 12; ++j) acc[r][j] = 0.f;

        #pragma unroll 4
        for (int mm = 0; mm < 32; ++mm) {
            const float4 w0 = P[0][mm][lane];
            const float4 w1 = P[1][mm][lane];
            const float4 w2 = P[2][mm][lane];
            const float4 hv = *(const float4*)&HT[bl][mm][k0];
            const float wj[12]  = {w0.x,w0.y,w0.z,w0.w, w1.x,w1.y,w1.z,w1.w,
                                   w2.x,w2.y,w2.z,w2.w};
            const float hr4[4]  = {hv.x, hv.y, hv.z, hv.w};
            #pragma unroll
            for (int r = 0; r < 4; ++r)
                #pragma unroll
                for (int j = 0; j < 12; ++j)
                    acc[r][j] = fmaf(hr4[r], wj[j], acc[r][j]);
        }

        // ---- write-key dot ww[r][p] = sum_f w_write[t][m_][f] * h_read[k][f]
        float ww[4][4];
        #pragma unroll
        for (int r = 0; r < 4; ++r)
            #pragma unroll
            for (int p = 0; p < 4; ++p) ww[r][p] = 0.f;
        #pragma unroll
        for (int f = 0; f < 16; ++f) {
            float wt[4], hk[4];
            #pragma unroll
            for (int p = 0; p < 4; ++p)
                wt[p] = WWT[(2 * p + half) * 512 + f * 32 + m_];
            #pragma unroll
            for (int r = 0; r < 4; ++r)
                hk[r] = HR2[bl][k0 + r][f];
            #pragma unroll
            for (int r = 0; r < 4; ++r)
                #pragma unroll
                for (int p = 0; p < 4; ++p)
                    ww[r][p] = fmaf(hk[r], wt[p], ww[r][p]);
        }

        // ---- per-k epilogue: gates, logits, argmax, gather
        #pragma unroll
        for (int r = 0; r < 4; ++r) {
            const int k = k0 + r;
            const float h2v = HT[bl][m_][k];
            float hn[4], lg[4];
            #pragma unroll
            for (int p = 0; p < 4; ++p) {
                const float xr = gi_r[p][0] + acc[r][p*3+0];
                const float xz = gi_r[p][1] + acc[r][p*3+1];
                const float gn = bhn[p]     + acc[r][p*3+2];
                const float rg = 1.f / (1.f + __expf(-xr));
                const float zg = 1.f / (1.f + __expf(-xz));
                const float xn = gi_r[p][2] + rg * gn;
                const float e2 = __expf(2.f * xn);
                const float tn = 1.f - 2.f / (e2 + 1.f);   // tanh
                const float hv2 = (1.f - zg) * tn + zg * h2v;
                hn[p] = hv2;
                float part = hv2 * ww[r][p];               // logit partial
                part += __shfl_xor(part, 1, 64);
                part += __shfl_xor(part, 2, 64);
                part += __shfl_xor(part, 4, 64);
                part += __shfl_xor(part, 8, 64);
                part += __shfl_xor(part, 16, 64);
                lg[p] = part;
            }
            float s[8];
            #pragma unroll
            for (int p = 0; p < 4; ++p) {
                const float oth = __shfl_xor(lg[p], 32, 64);
                s[2*p]   = half ? oth   : lg[p];
                s[2*p+1] = half ? lg[p] : oth;
            }
            const float* gp = gumb + ((size_t)b * NB_K + k) * NB_T;
            float best = s[0] + gp[0]; int bt = 0;
            #pragma unroll
            for (int t2 = 1; t2 < 8; ++t2) {
                const float v = s[t2] + gp[t2];
                if (v > best) { best = v; bt = t2; }   // first-max argmax
            }
            const int pstar = bt >> 1, hstar = bt & 1;
            float hsel = hn[0];
            hsel = (pstar == 1) ? hn[1] : hsel;
            hsel = (pstar == 2) ? hn[2] : hsel;
            hsel = (pstar == 3) ? hn[3] : hsel;
            if (half == hstar)
                out[(size_t)b * NB_NHID + k * 32 + m_] = hsel;
            if (lane < 8)
                out[H_OUT_ELEMS + ((size_t)b * NB_K + k) * NB_T + lane] =
                    (lane == bt) ? 1.f : 0.f;
        }
    }
}

extern "C" void kernel_launch(void* const* d_in, const int* in_sizes, int n_in,
                              void* d_out, int out_size, void* d_ws, size_t ws_size,
                              hipStream_t stream) {
    const float* x      = (const float*)d_in[0];
    const float* h      = (const float*)d_in[1];
    const float* Wih    = (const float*)d_in[2];
    const float* Whh    = (const float*)d_in[3];
    const float* bih    = (const float*)d_in[4];
    const float* bhh    = (const float*)d_in[5];
    const float* wread  = (const float*)d_in[6];
    const float* wwrite = (const float*)d_in[7];
    const float* gumb   = (const float*)d_in[8];
    float* out = (float*)d_out;
    float* gi  = (float*)d_ws;   // 2048*768*4 = 6 MB scratch

    k1_gemm_gi<<<dim3(32, 8), 256, 0, stream>>>(x, Wih, bih, bhh, gi);
    k2_fused<<<dim3(256), 1024, 0, stream>>>(h, Whh, bhh, wread, wwrite,
                                             gumb, gi, out);
}

// Round 3
// 229.690 us; speedup vs baseline: 1.0368x; 1.0368x over previous
//
#include <hip/hip_runtime.h>

#define NB_BS   2048
#define NB_NINP 512
#define NB_NHID 512
#define NB_K    16
#define NB_T    8
#define NB_M    32
#define NB_C    768   // T * 3 * M
#define H_OUT_ELEMS (NB_BS * NB_NHID)   // 1048576

// ---------------------------------------------------------------------------
// Kernel 1: gi'[b][c] = sum_i x[b][i]*Wih[c][i] + bih[c] + (gate<2 ? bhh[c] : 0)
// 64x96 tile, BK=32, 256 threads, 4x6 micro-tile. Grid = 32x8 = 256 blocks
// (exactly 1/CU, perfectly balanced). bhh for r,z gates folded here so k2's
// epilogue only needs bhh_n.
// ---------------------------------------------------------------------------
__global__ __launch_bounds__(256)
void k1_gemm_gi(const float* __restrict__ x, const float* __restrict__ Wih,
                const float* __restrict__ bih, const float* __restrict__ bhh,
                float* __restrict__ gi)
{
    __shared__ __align__(16) float As[32][68];    // [k][row]
    __shared__ __align__(16) float Bs[32][100];   // [k][col]

    const int tid  = threadIdx.x;
    const int row0 = blockIdx.x * 64;
    const int col0 = blockIdx.y * 96;
    const int lrow = tid >> 2;            // 0..63
    const int lk   = (tid & 3) * 8;       // 0,8,16,24
    const int tr   = tid >> 4;            // 0..15 -> rows tr*4..
    const int tc   = tid & 15;            // 0..15 -> cols tc*6..

    const int c0 = tid >> 3,          kq0 = (tid & 7) * 4;
    const int c1 = (tid + 256) >> 3,  kq1 = ((tid + 256) & 7) * 4;
    const int c2 = (tid + 512) >> 3,  kq2 = ((tid + 512) & 7) * 4;

    const float* xp = x + (size_t)(row0 + lrow) * NB_NINP + lk;
    float4 a0 = *(const float4*)xp;
    float4 a1 = *(const float4*)(xp + 4);
    float4 b0 = *(const float4*)&Wih[(size_t)(col0 + c0) * NB_NINP + kq0];
    float4 b1 = *(const float4*)&Wih[(size_t)(col0 + c1) * NB_NINP + kq1];
    float4 b2 = *(const float4*)&Wih[(size_t)(col0 + c2) * NB_NINP + kq2];

    float acc[4][6];
    #pragma unroll
    for (int i = 0; i < 4; ++i)
        #pragma unroll
        for (int e = 0; e < 6; ++e) acc[i][e] = 0.f;

    for (int kb = 0; kb < NB_NINP; kb += 32) {
        __syncthreads();
        As[lk+0][lrow]=a0.x; As[lk+1][lrow]=a0.y; As[lk+2][lrow]=a0.z; As[lk+3][lrow]=a0.w;
        As[lk+4][lrow]=a1.x; As[lk+5][lrow]=a1.y; As[lk+6][lrow]=a1.z; As[lk+7][lrow]=a1.w;
        Bs[kq0+0][c0]=b0.x; Bs[kq0+1][c0]=b0.y; Bs[kq0+2][c0]=b0.z; Bs[kq0+3][c0]=b0.w;
        Bs[kq1+0][c1]=b1.x; Bs[kq1+1][c1]=b1.y; Bs[kq1+2][c1]=b1.z; Bs[kq1+3][c1]=b1.w;
        Bs[kq2+0][c2]=b2.x; Bs[kq2+1][c2]=b2.y; Bs[kq2+2][c2]=b2.z; Bs[kq2+3][c2]=b2.w;
        __syncthreads();
        if (kb + 32 < NB_NINP) {    // prefetch next K-slab into regs
            a0 = *(const float4*)(xp + kb + 32);
            a1 = *(const float4*)(xp + kb + 36);
            b0 = *(const float4*)&Wih[(size_t)(col0 + c0) * NB_NINP + kb + 32 + kq0];
            b1 = *(const float4*)&Wih[(size_t)(col0 + c1) * NB_NINP + kb + 32 + kq1];
            b2 = *(const float4*)&Wih[(size_t)(col0 + c2) * NB_NINP + kb + 32 + kq2];
        }
        #pragma unroll
        for (int kk = 0; kk < 32; ++kk) {
            const float4 av = *(const float4*)&As[kk][tr * 4];
            const float2 w0 = *(const float2*)&Bs[kk][tc * 6];
            const float2 w1 = *(const float2*)&Bs[kk][tc * 6 + 2];
            const float2 w2 = *(const float2*)&Bs[kk][tc * 6 + 4];
            const float avv[4] = {av.x, av.y, av.z, av.w};
            const float wvv[6] = {w0.x, w0.y, w1.x, w1.y, w2.x, w2.y};
            #pragma unroll
            for (int i = 0; i < 4; ++i)
                #pragma unroll
                for (int e = 0; e < 6; ++e)
                    acc[i][e] = fmaf(avv[i], wvv[e], acc[i][e]);
        }
    }

    float bias[6];
    #pragma unroll
    for (int e = 0; e < 6; ++e) {
        const int cl = tc * 6 + e;        // == c % 96 since col0 % 96 == 0
        const int c  = col0 + cl;
        bias[e] = bih[c] + (cl < 64 ? bhh[c] : 0.f);
    }
    #pragma unroll
    for (int i = 0; i < 4; ++i) {
        const size_t base = (size_t)(row0 + tr * 4 + i) * NB_C + col0 + tc * 6;
        #pragma unroll
        for (int e = 0; e < 6; ++e) gi[base + e] = acc[i][e] + bias[e];
    }
}

// ---------------------------------------------------------------------------
// Kernel 2: fused gh-GEMM + GRU gates + write-key logits + gumbel-argmax +
// gather. 256 blocks x 1024 threads (16 waves = 4 waves/SIMD).
// __launch_bounds__(1024, 4): min 4 waves/EU -> VGPR cap 128 (NOT 64 -- the
// round-2 regression was the compiler picking 64 VGPRs and spilling acc to
// scratch: FETCH_SIZE 252 MB). LDS caps us at 1 block/CU anyway.
// P planes XOR-swizzled by (mm&7) on the float4 slot: staging writes go
// 32-way -> <=8-way bank conflict; reads remain a permutation of the full
// row -> conflict-free.
// ---------------------------------------------------------------------------
__global__ __launch_bounds__(1024, 4)
void k2_fused(const float* __restrict__ h,      const float* __restrict__ Whh,
              const float* __restrict__ bhh,    const float* __restrict__ wread,
              const float* __restrict__ wwrite, const float* __restrict__ gumb,
              const float* __restrict__ gi,     float* __restrict__ out)
{
    __shared__ __align__(16) float4 P[3][32][64];   // 98304 B  W_hh planes
    __shared__ float WWT[NB_T * 16 * 32];           // 16384 B  [t][f][m]
    __shared__ float WR[512];                       //  2048 B  [m][f]
    __shared__ __align__(16) float HT[8][32][20];   // 20480 B  [bl][m][k]
    __shared__ __align__(16) float HR2[8][16][20];  // 10240 B  [bl][k][f]

    const int tid  = threadIdx.x;
    const int wave = tid >> 6, lane = tid & 63;
    const int bl   = wave >> 1, kh = wave & 1;
    const int b    = blockIdx.x * 8 + bl;
    const int m_   = lane & 31, half = lane >> 5;

    // ---- stage W_hh into planes: value for (reading-lane sl, j=p*3+gc) at
    //      contraction mm lands at slot (sl ^ (mm&7)) of row [j>>2][mm].
    float* PF = (float*)P;
    for (int i = tid; i < 24576; i += 1024) {       // Whh flat [c][m]; c=t*96+gc*32+mout
        const int c = i >> 5, mm = i & 31;
        const int t = c / 96, rem = c - t * 96;
        const int gc = rem >> 5, mout = rem & 31;
        const int j  = (t >> 1) * 3 + gc;
        const int sl = ((t & 1) * 32 + mout) ^ (mm & 7);   // swizzled slot
        PF[(((j >> 2) * 32 + mm) * 64 + sl) * 4 + (j & 3)] = Whh[i];
    }
    for (int i = tid; i < 4096; i += 1024) {        // wwrite flat [t][m][f]
        const int t = i >> 9, mo = (i >> 4) & 31, f = i & 15;
        WWT[t * 512 + f * 32 + mo] = wwrite[i];
    }
    if (tid < 512) WR[tid] = wread[tid];
    #pragma unroll
    for (int e = 0; e < 4; ++e) {                   // this wave's h half-row, transposed
        const int idx = kh * 256 + e * 64 + lane;
        HT[bl][idx & 31][idx >> 5] = h[(size_t)b * NB_NHID + idx];
    }
    __syncthreads();

    // ---- h_read for this wave's 8 k's: lane owns (k, f-pair)
    {
        const int kq = kh * 8 + (lane >> 3);
        const int f0 = (lane & 7) * 2;
        float s0 = 0.f, s1 = 0.f;
        #pragma unroll
        for (int mm = 0; mm < 32; ++mm) {
            const float hv = HT[bl][mm][kq];
            s0 = fmaf(hv, WR[mm * 16 + f0], s0);
            s1 = fmaf(hv, WR[mm * 16 + f0 + 1], s1);
        }
        HR2[bl][kq][f0]     = s0;
        HR2[bl][kq][f0 + 1] = s1;
    }

    // ---- per-lane gi' (bih + bhh_{r,z} already folded by k1) and bhh_n
    float gi_r[4][3], bhn[4];
    #pragma unroll
    for (int p = 0; p < 4; ++p) {
        const int t = 2 * p + half;
        #pragma unroll
        for (int gc = 0; gc < 3; ++gc)
            gi_r[p][gc] = gi[(size_t)b * NB_C + t * 96 + gc * 32 + m_];
        bhn[p] = bhh[t * 96 + 64 + m_];
    }

    #pragma unroll 1
    for (int pass = 0; pass < 2; ++pass) {
        const int k0 = kh * 8 + pass * 4;

        // ---- gh GEMM for 4 k's: 48 FMA per mm, 4 conflict-free b128 reads
        float acc[4][12];
        #pragma unroll
        for (int r = 0; r < 4; ++r)
            #pragma unroll
            for (int j = 0; j < 12; ++j) acc[r][j] = 0.f;

        #pragma unroll 4
        for (int mm = 0; mm < 32; ++mm) {
            const int sw = lane ^ (mm & 7);         // undo staging swizzle
            const float4 w0 = P[0][mm][sw];
            const float4 w1 = P[1][mm][sw];
            const float4 w2 = P[2][mm][sw];
            const float4 hv = *(const float4*)&HT[bl][mm][k0];
            const float wj[12]  = {w0.x,w0.y,w0.z,w0.w, w1.x,w1.y,w1.z,w1.w,
                                   w2.x,w2.y,w2.z,w2.w};
            const float hr4[4]  = {hv.x, hv.y, hv.z, hv.w};
            #pragma unroll
            for (int r = 0; r < 4; ++r)
                #pragma unroll
                for (int j = 0; j < 12; ++j)
                    acc[r][j] = fmaf(hr4[r], wj[j], acc[r][j]);
        }

        // ---- write-key dot ww[r][p] = sum_f w_write[t][m_][f] * h_read[k][f]
        float ww[4][4];
        #pragma unroll
        for (int r = 0; r < 4; ++r)
            #pragma unroll
            for (int p = 0; p < 4; ++p) ww[r][p] = 0.f;
        #pragma unroll
        for (int f = 0; f < 16; ++f) {
            float wt[4], hk[4];
            #pragma unroll
            for (int p = 0; p < 4; ++p)
                wt[p] = WWT[(2 * p + half) * 512 + f * 32 + m_];
            #pragma unroll
            for (int r = 0; r < 4; ++r)
                hk[r] = HR2[bl][k0 + r][f];
            #pragma unroll
            for (int r = 0; r < 4; ++r)
                #pragma unroll
                for (int p = 0; p < 4; ++p)
                    ww[r][p] = fmaf(hk[r], wt[p], ww[r][p]);
        }

        // ---- per-k epilogue: gates, logits, argmax, gather
        #pragma unroll
        for (int r = 0; r < 4; ++r) {
            const int k = k0 + r;
            const float h2v = HT[bl][m_][k];
            float hn[4], lg[4];
            #pragma unroll
            for (int p = 0; p < 4; ++p) {
                const float xr = gi_r[p][0] + acc[r][p*3+0];
                const float xz = gi_r[p][1] + acc[r][p*3+1];
                const float gn = bhn[p]     + acc[r][p*3+2];
                const float rg = 1.f / (1.f + __expf(-xr));
                const float zg = 1.f / (1.f + __expf(-xz));
                const float xn = gi_r[p][2] + rg * gn;
                const float e2 = __expf(2.f * xn);
                const float tn = 1.f - 2.f / (e2 + 1.f);   // tanh
                const float hv2 = (1.f - zg) * tn + zg * h2v;
                hn[p] = hv2;
                float part = hv2 * ww[r][p];               // logit partial
                part += __shfl_xor(part, 1, 64);
                part += __shfl_xor(part, 2, 64);
                part += __shfl_xor(part, 4, 64);
                part += __shfl_xor(part, 8, 64);
                part += __shfl_xor(part, 16, 64);
                lg[p] = part;
            }
            float s[8];
            #pragma unroll
            for (int p = 0; p < 4; ++p) {
                const float oth = __shfl_xor(lg[p], 32, 64);
                s[2*p]   = half ? oth   : lg[p];
                s[2*p+1] = half ? lg[p] : oth;
            }
            const float* gp = gumb + ((size_t)b * NB_K + k) * NB_T;
            float best = s[0] + gp[0]; int bt = 0;
            #pragma unroll
            for (int t2 = 1; t2 < 8; ++t2) {
                const float v = s[t2] + gp[t2];
                if (v > best) { best = v; bt = t2; }   // first-max argmax
            }
            const int pstar = bt >> 1, hstar = bt & 1;
            float hsel = hn[0];
            hsel = (pstar == 1) ? hn[1] : hsel;
            hsel = (pstar == 2) ? hn[2] : hsel;
            hsel = (pstar == 3) ? hn[3] : hsel;
            if (half == hstar)
                out[(size_t)b * NB_NHID + k * 32 + m_] = hsel;
            if (lane < 8)
                out[H_OUT_ELEMS + ((size_t)b * NB_K + k) * NB_T + lane] =
                    (lane == bt) ? 1.f : 0.f;
        }
    }
}

extern "C" void kernel_launch(void* const* d_in, const int* in_sizes, int n_in,
                              void* d_out, int out_size, void* d_ws, size_t ws_size,
                              hipStream_t stream) {
    const float* x      = (const float*)d_in[0];
    const float* h      = (const float*)d_in[1];
    const float* Wih    = (const float*)d_in[2];
    const float* Whh    = (const float*)d_in[3];
    const float* bih    = (const float*)d_in[4];
    const float* bhh    = (const float*)d_in[5];
    const float* wread  = (const float*)d_in[6];
    const float* wwrite = (const float*)d_in[7];
    const float* gumb   = (const float*)d_in[8];
    float* out = (float*)d_out;
    float* gi  = (float*)d_ws;   // 2048*768*4 = 6 MB scratch

    k1_gemm_gi<<<dim3(32, 8), 256, 0, stream>>>(x, Wih, bih, bhh, gi);
    k2_fused<<<dim3(256), 1024, 0, stream>>>(h, Whh, bhh, wread, wwrite,
                                             gumb, gi, out);
}

// Round 4
// 99.743 us; speedup vs baseline: 2.3876x; 2.3028x over previous
//
#include <hip/hip_runtime.h>

#define NB_BS   2048
#define NB_NINP 512
#define NB_NHID 512
#define NB_K    16
#define NB_T    8
#define NB_M    32
#define NB_C    768   // T * 3 * M
#define H_OUT_ELEMS (NB_BS * NB_NHID)   // 1048576

// ---------------------------------------------------------------------------
// Kernel 1: gi'[b][c] = sum_i x[b][i]*Wih[c][i] + bih[c] + (gate<2 ? bhh[c] : 0)
// 64x96 tile, BK=32, 256 threads, grid 32x8 = 256 blocks (1/CU, balanced).
// Grouped LDS addressing: wave = 16 row-groups x 4 col-groups, so the av b128
// has 16 distinct addresses (2 lanes/bank = free) and wv has 4 -> LDS cost
// ~6 cyc per 48 FMA-cyc (round-1 layout was 61K LDS cyc/CU = the real k1
// bottleneck). Micro-tile 4x6 via b64 reads (cg*6 is 8B- not 16B-aligned).
// ---------------------------------------------------------------------------
__global__ __launch_bounds__(256, 4)
void k1_gemm_gi(const float* __restrict__ x, const float* __restrict__ Wih,
                const float* __restrict__ bih, const float* __restrict__ bhh,
                float* __restrict__ gi)
{
    __shared__ __align__(16) float As[32][68];    // [k][row]
    __shared__ __align__(16) float Bs[32][100];   // [k][col]

    const int tid  = threadIdx.x;
    const int row0 = blockIdx.x * 64;
    const int col0 = blockIdx.y * 96;
    const int wave = tid >> 6, lane = tid & 63;
    const int rg   = lane >> 2;           // 0..15 -> rows rg*4..rg*4+3
    const int cg   = lane & 3;            // 0..3
    const int wc0  = wave * 24 + cg * 6;  // col within tile

    const int lrow = tid >> 2;            // staging: 0..63
    const int lk   = (tid & 3) * 8;       // 0,8,16,24

    const int c0 = tid >> 3,          kq0 = (tid & 7) * 4;
    const int c1 = (tid + 256) >> 3,  kq1 = ((tid + 256) & 7) * 4;
    const int c2 = (tid + 512) >> 3,  kq2 = ((tid + 512) & 7) * 4;

    const float* xp = x + (size_t)(row0 + lrow) * NB_NINP + lk;
    float4 a0 = *(const float4*)xp;
    float4 a1 = *(const float4*)(xp + 4);
    float4 b0 = *(const float4*)&Wih[(size_t)(col0 + c0) * NB_NINP + kq0];
    float4 b1 = *(const float4*)&Wih[(size_t)(col0 + c1) * NB_NINP + kq1];
    float4 b2 = *(const float4*)&Wih[(size_t)(col0 + c2) * NB_NINP + kq2];

    float acc[4][6];
    #pragma unroll
    for (int i = 0; i < 4; ++i)
        #pragma unroll
        for (int e = 0; e < 6; ++e) acc[i][e] = 0.f;

    for (int kb = 0; kb < NB_NINP; kb += 32) {
        __syncthreads();
        As[lk+0][lrow]=a0.x; As[lk+1][lrow]=a0.y; As[lk+2][lrow]=a0.z; As[lk+3][lrow]=a0.w;
        As[lk+4][lrow]=a1.x; As[lk+5][lrow]=a1.y; As[lk+6][lrow]=a1.z; As[lk+7][lrow]=a1.w;
        Bs[kq0+0][c0]=b0.x; Bs[kq0+1][c0]=b0.y; Bs[kq0+2][c0]=b0.z; Bs[kq0+3][c0]=b0.w;
        Bs[kq1+0][c1]=b1.x; Bs[kq1+1][c1]=b1.y; Bs[kq1+2][c1]=b1.z; Bs[kq1+3][c1]=b1.w;
        Bs[kq2+0][c2]=b2.x; Bs[kq2+1][c2]=b2.y; Bs[kq2+2][c2]=b2.z; Bs[kq2+3][c2]=b2.w;
        __syncthreads();
        if (kb + 32 < NB_NINP) {    // prefetch next K-slab into regs
            a0 = *(const float4*)(xp + kb + 32);
            a1 = *(const float4*)(xp + kb + 36);
            b0 = *(const float4*)&Wih[(size_t)(col0 + c0) * NB_NINP + kb + 32 + kq0];
            b1 = *(const float4*)&Wih[(size_t)(col0 + c1) * NB_NINP + kb + 32 + kq1];
            b2 = *(const float4*)&Wih[(size_t)(col0 + c2) * NB_NINP + kb + 32 + kq2];
        }
        #pragma unroll
        for (int kk = 0; kk < 32; ++kk) {
            const float4 av = *(const float4*)&As[kk][rg * 4];
            const float2 w0 = *(const float2*)&Bs[kk][wc0];
            const float2 w1 = *(const float2*)&Bs[kk][wc0 + 2];
            const float2 w2 = *(const float2*)&Bs[kk][wc0 + 4];
            const float avv[4] = {av.x, av.y, av.z, av.w};
            const float wvv[6] = {w0.x, w0.y, w1.x, w1.y, w2.x, w2.y};
            #pragma unroll
            for (int i = 0; i < 4; ++i)
                #pragma unroll
                for (int e = 0; e < 6; ++e)
                    acc[i][e] = fmaf(avv[i], wvv[e], acc[i][e]);
        }
    }

    float bias[6];
    #pragma unroll
    for (int e = 0; e < 6; ++e) {
        const int cl = wc0 + e;
        const int c  = col0 + cl;
        bias[e] = bih[c] + (cl < 64 ? bhh[c] : 0.f);
    }
    #pragma unroll
    for (int i = 0; i < 4; ++i) {
        const size_t base = (size_t)(row0 + rg * 4 + i) * NB_C + col0 + wc0;
        #pragma unroll
        for (int e = 0; e < 6; ++e) gi[base + e] = acc[i][e] + bias[e];
    }
}

// ---------------------------------------------------------------------------
// Kernel 2: fused gh-GEMM + GRU + write-key logits + gumbel-argmax + gather.
// 256 blocks x 512 threads, wave = one b. __launch_bounds__(512,2): VGPR cap
// 256 (round-2/3 lesson: 1024-thr blocks get squeezed to 64 VGPR and spill
// ~1KB/thread to scratch = 250MB HBM). LDS 147KB caps 1 block/CU = 2
// waves/SIMD regardless, so high VGPR costs nothing.
// Per wave: 2 k-octet passes, acc[8][12] (96 regs, round-1-proven no-spill).
// Inner mm step: 3 spread b128 (P, swizzled) + 2 broadcast b128 (hv) for
// 96 FMA. ww computed per p-pair AFTER the mm loop (acc live, ww only 16
// regs); gi'/bhh_n reloaded from L3 per pass instead of held live.
// ---------------------------------------------------------------------------
__global__ __launch_bounds__(512, 2)
void k2_fused(const float* __restrict__ h,      const float* __restrict__ Whh,
              const float* __restrict__ bhh,    const float* __restrict__ wread,
              const float* __restrict__ wwrite, const float* __restrict__ gumb,
              const float* __restrict__ gi,     float* __restrict__ out)
{
    __shared__ __align__(16) float4 P[3][32][64];   // 98304 B  W_hh planes
    __shared__ float WWT[NB_T * 16 * 32];           // 16384 B  [t][f][m]
    __shared__ __align__(16) float WR[512];         //  2048 B  [m][f]
    __shared__ __align__(16) float HT[8][32][20];   // 20480 B  [bl][m][k]
    __shared__ __align__(16) float HR2T[8][16][20]; // 10240 B  [bl][f][k]

    const int tid  = threadIdx.x;
    const int wave = tid >> 6, lane = tid & 63;
    const int bl   = wave;
    const int b    = blockIdx.x * 8 + bl;
    const int m_   = lane & 31, half = lane >> 5;

    // ---- stage W_hh planes (value for reading-lane sl at contraction mm
    //      lands at float4 slot sl ^ (mm&7) of row [j>>2][mm])
    float* PF = (float*)P;
    for (int i = tid; i < 24576; i += 512) {        // Whh flat [c][m]; c=t*96+gc*32+mout
        const int c = i >> 5, mm = i & 31;
        const int t = c / 96, rem = c - t * 96;
        const int gc = rem >> 5, mout = rem & 31;
        const int j  = (t >> 1) * 3 + gc;
        const int sl = ((t & 1) * 32 + mout) ^ (mm & 7);
        PF[(((j >> 2) * 32 + mm) * 64 + sl) * 4 + (j & 3)] = Whh[i];
    }
    for (int i = tid; i < 4096; i += 512) {         // wwrite flat [t][m][f]
        const int t = i >> 9, mo = (i >> 4) & 31, f = i & 15;
        WWT[t * 512 + f * 32 + mo] = wwrite[i];
    }
    if (tid < 512) WR[tid] = wread[tid];
    #pragma unroll
    for (int e = 0; e < 8; ++e) {                   // h row transposed: HT[m][k]
        const int idx = e * 64 + lane;
        HT[bl][idx & 31][idx >> 5] = h[(size_t)b * NB_NHID + idx];
    }
    __syncthreads();   // all LDS below is read-only except wave-local HR2T

    // ---- h_read (wave-local): lane owns (k = lane>>2, f-quad = (lane&3)*4)
    {
        const int kq = lane >> 2;
        const int f0 = (lane & 3) * 4;
        float s0 = 0.f, s1 = 0.f, s2 = 0.f, s3 = 0.f;
        #pragma unroll 8
        for (int mm = 0; mm < 32; ++mm) {
            const float  hv = HT[bl][mm][kq];
            const float4 wr = *(const float4*)&WR[mm * 16 + f0];
            s0 = fmaf(hv, wr.x, s0); s1 = fmaf(hv, wr.y, s1);
            s2 = fmaf(hv, wr.z, s2); s3 = fmaf(hv, wr.w, s3);
        }
        HR2T[bl][f0    ][kq] = s0;
        HR2T[bl][f0 + 1][kq] = s1;
        HR2T[bl][f0 + 2][kq] = s2;
        HR2T[bl][f0 + 3][kq] = s3;
    }

    float hn[8][4], lg[8][4];

    #pragma unroll 1
    for (int kk = 0; kk < 2; ++kk) {
        const int k0 = kk * 8;

        // ---- gh GEMM, 8 k's: 96 FMA per mm; 3 spread b128 + 2 broadcast b128
        float acc[8][12];
        #pragma unroll
        for (int r = 0; r < 8; ++r)
            #pragma unroll
            for (int j = 0; j < 12; ++j) acc[r][j] = 0.f;

        #pragma unroll 2
        for (int mm = 0; mm < 32; ++mm) {
            const int sw = lane ^ (mm & 7);          // undo staging swizzle
            const float4 w0 = P[0][mm][sw];
            const float4 w1 = P[1][mm][sw];
            const float4 w2 = P[2][mm][sw];
            const float4 ha = *(const float4*)&HT[bl][mm][k0];      // broadcast
            const float4 hb = *(const float4*)&HT[bl][mm][k0 + 4];  // broadcast
            const float wj[12] = {w0.x,w0.y,w0.z,w0.w, w1.x,w1.y,w1.z,w1.w,
                                  w2.x,w2.y,w2.z,w2.w};
            const float hr8[8] = {ha.x,ha.y,ha.z,ha.w, hb.x,hb.y,hb.z,hb.w};
            #pragma unroll
            for (int r = 0; r < 8; ++r)
                #pragma unroll
                for (int j = 0; j < 12; ++j)
                    acc[r][j] = fmaf(hr8[r], wj[j], acc[r][j]);
        }

        // ---- per-lane gi' (bih+bhh_{r,z} folded by k1) and bhh_n, from L3
        float gi_r[4][3], bhn[4];
        #pragma unroll
        for (int p = 0; p < 4; ++p) {
            const int t = 2 * p + half;
            #pragma unroll
            for (int gc = 0; gc < 3; ++gc)
                gi_r[p][gc] = gi[(size_t)b * NB_C + t * 96 + gc * 32 + m_];
            bhn[p] = bhh[t * 96 + 64 + m_];
        }

        // ---- p-pairs: ww (16 regs) then gates+logits for p = 2jj, 2jj+1
        #pragma unroll
        for (int jj = 0; jj < 2; ++jj) {
            const int t0 = 4 * jj + half;            // t for q=0
            const int t1 = 4 * jj + 2 + half;        // t for q=1
            float ww[8][2];
            #pragma unroll
            for (int r = 0; r < 8; ++r) { ww[r][0] = 0.f; ww[r][1] = 0.f; }
            #pragma unroll 4
            for (int f = 0; f < 16; ++f) {
                const float wt0 = WWT[t0 * 512 + f * 32 + m_];
                const float wt1 = WWT[t1 * 512 + f * 32 + m_];
                const float4 hka = *(const float4*)&HR2T[bl][f][k0];      // bc
                const float4 hkb = *(const float4*)&HR2T[bl][f][k0 + 4];  // bc
                const float hk[8] = {hka.x,hka.y,hka.z,hka.w,
                                     hkb.x,hkb.y,hkb.z,hkb.w};
                #pragma unroll
                for (int r = 0; r < 8; ++r) {
                    ww[r][0] = fmaf(hk[r], wt0, ww[r][0]);
                    ww[r][1] = fmaf(hk[r], wt1, ww[r][1]);
                }
            }
            #pragma unroll
            for (int r = 0; r < 8; ++r) {
                const int k = k0 + r;
                const float h2v = HT[bl][m_][k];
                #pragma unroll
                for (int q = 0; q < 2; ++q) {
                    const int p = 2 * jj + q;
                    const float xr = gi_r[p][0] + acc[r][p*3+0];
                    const float xz = gi_r[p][1] + acc[r][p*3+1];
                    const float gn = bhn[p]     + acc[r][p*3+2];
                    const float rg = 1.f / (1.f + __expf(-xr));
                    const float zg = 1.f / (1.f + __expf(-xz));
                    const float xn = gi_r[p][2] + rg * gn;
                    const float e2 = __expf(2.f * xn);
                    const float tn = 1.f - 2.f / (e2 + 1.f);   // tanh
                    const float hv2 = (1.f - zg) * tn + zg * h2v;
                    hn[r][p] = hv2;
                    float part = hv2 * ww[r][q];               // logit partial
                    part += __shfl_xor(part, 1, 64);
                    part += __shfl_xor(part, 2, 64);
                    part += __shfl_xor(part, 4, 64);
                    part += __shfl_xor(part, 8, 64);
                    part += __shfl_xor(part, 16, 64);
                    lg[r][p] = part;
                }
            }
        }

        // ---- finale per k: assemble logits, gumbel-argmax, gather + one-hot
        #pragma unroll
        for (int r = 0; r < 8; ++r) {
            const int k = k0 + r;
            float s[8];
            #pragma unroll
            for (int p = 0; p < 4; ++p) {
                const float oth = __shfl_xor(lg[r][p], 32, 64);
                s[2*p]   = half ? oth      : lg[r][p];
                s[2*p+1] = half ? lg[r][p] : oth;
            }
            const float* gp = gumb + ((size_t)b * NB_K + k) * NB_T;
            const float4 ga = *(const float4*)gp;
            const float4 gb = *(const float4*)(gp + 4);
            const float gv[8] = {ga.x,ga.y,ga.z,ga.w, gb.x,gb.y,gb.z,gb.w};
            float best = s[0] + gv[0]; int bt = 0;
            #pragma unroll
            for (int t2 = 1; t2 < 8; ++t2) {
                const float v = s[t2] + gv[t2];
                if (v > best) { best = v; bt = t2; }   // first-max argmax
            }
            const int pstar = bt >> 1, hstar = bt & 1;
            float hsel = hn[r][0];
            hsel = (pstar == 1) ? hn[r][1] : hsel;
            hsel = (pstar == 2) ? hn[r][2] : hsel;
            hsel = (pstar == 3) ? hn[r][3] : hsel;
            if (half == hstar)
                out[(size_t)b * NB_NHID + k * 32 + m_] = hsel;
            if (lane < 8)
                out[H_OUT_ELEMS + ((size_t)b * NB_K + k) * NB_T + lane] =
                    (lane == bt) ? 1.f : 0.f;
        }
    }
}

extern "C" void kernel_launch(void* const* d_in, const int* in_sizes, int n_in,
                              void* d_out, int out_size, void* d_ws, size_t ws_size,
                              hipStream_t stream) {
    const float* x      = (const float*)d_in[0];
    const float* h      = (const float*)d_in[1];
    const float* Wih    = (const float*)d_in[2];
    const float* Whh    = (const float*)d_in[3];
    const float* bih    = (const float*)d_in[4];
    const float* bhh    = (const float*)d_in[5];
    const float* wread  = (const float*)d_in[6];
    const float* wwrite = (const float*)d_in[7];
    const float* gumb   = (const float*)d_in[8];
    float* out = (float*)d_out;
    float* gi  = (float*)d_ws;   // 2048*768*4 = 6 MB scratch

    k1_gemm_gi<<<dim3(32, 8), 256, 0, stream>>>(x, Wih, bih, bhh, gi);
    k2_fused<<<dim3(256), 512, 0, stream>>>(h, Whh, bhh, wread, wwrite,
                                            gumb, gi, out);
}

// Round 5
// 96.345 us; speedup vs baseline: 2.4718x; 1.0353x over previous
//
#include <hip/hip_runtime.h>

#define NB_BS   2048
#define NB_NINP 512
#define NB_NHID 512
#define NB_K    16
#define NB_T    8
#define NB_M    32
#define NB_C    768   // T * 3 * M
#define H_OUT_ELEMS (NB_BS * NB_NHID)   // 1048576

// ---------------------------------------------------------------------------
// Kernel 1: gi'[b][c] = sum_i x[b][i]*Wih[c][i] + bih[c] + (gate<2 ? bhh[c] : 0)
// 32x96 tile, BK=32, 256 threads, 2x6 micro-tile. Grid (64 rows, 8 cols) =
// 512 blocks = 2 blocks/CU = 2 waves/SIMD (round-4 k1 ran 1 wave/SIMD and was
// latency-bound at ~33us vs a 10.2us VALU floor). blockIdx.x = row block so
// the 8 col-blocks sharing x rows land on the same XCD (dispatch id % 8).
// ---------------------------------------------------------------------------
__global__ __launch_bounds__(256, 2)
void k1_gemm_gi(const float* __restrict__ x, const float* __restrict__ Wih,
                const float* __restrict__ bih, const float* __restrict__ bhh,
                float* __restrict__ gi)
{
    __shared__ __align__(16) float As[32][34];    // [k][row], pad 34 keeps 8B align
    __shared__ __align__(16) float Bs[32][100];   // [k][col]

    const int tid  = threadIdx.x;
    const int row0 = blockIdx.x * 32;     // 64 row blocks
    const int col0 = blockIdx.y * 96;     // 8 col blocks
    const int wave = tid >> 6, lane = tid & 63;
    const int rg   = lane >> 2;           // 0..15 -> rows rg*2, rg*2+1
    const int cg   = lane & 3;            // 0..3
    const int wc0  = wave * 24 + cg * 6;  // col within tile

    // As staging: thread -> (row = tid>>3 in 0..31, kq = (tid&7)*4)
    const int arow = tid >> 3, akq = (tid & 7) * 4;
    // Bs staging: 3 rounds of 256 float4s over 96 cols x 32 k
    const int c0 = tid >> 3,          kq0 = (tid & 7) * 4;
    const int c1 = (tid + 256) >> 3,  kq1 = ((tid + 256) & 7) * 4;
    const int c2 = (tid + 512) >> 3,  kq2 = ((tid + 512) & 7) * 4;

    const float* xp = x + (size_t)(row0 + arow) * NB_NINP + akq;
    float4 a0 = *(const float4*)xp;
    float4 b0 = *(const float4*)&Wih[(size_t)(col0 + c0) * NB_NINP + kq0];
    float4 b1 = *(const float4*)&Wih[(size_t)(col0 + c1) * NB_NINP + kq1];
    float4 b2 = *(const float4*)&Wih[(size_t)(col0 + c2) * NB_NINP + kq2];

    float acc[2][6];
    #pragma unroll
    for (int i = 0; i < 2; ++i)
        #pragma unroll
        for (int e = 0; e < 6; ++e) acc[i][e] = 0.f;

    for (int kb = 0; kb < NB_NINP; kb += 32) {
        __syncthreads();
        As[akq+0][arow]=a0.x; As[akq+1][arow]=a0.y;
        As[akq+2][arow]=a0.z; As[akq+3][arow]=a0.w;
        Bs[kq0+0][c0]=b0.x; Bs[kq0+1][c0]=b0.y; Bs[kq0+2][c0]=b0.z; Bs[kq0+3][c0]=b0.w;
        Bs[kq1+0][c1]=b1.x; Bs[kq1+1][c1]=b1.y; Bs[kq1+2][c1]=b1.z; Bs[kq1+3][c1]=b1.w;
        Bs[kq2+0][c2]=b2.x; Bs[kq2+1][c2]=b2.y; Bs[kq2+2][c2]=b2.z; Bs[kq2+3][c2]=b2.w;
        __syncthreads();
        if (kb + 32 < NB_NINP) {    // prefetch next K-slab into regs
            a0 = *(const float4*)(xp + kb + 32);
            b0 = *(const float4*)&Wih[(size_t)(col0 + c0) * NB_NINP + kb + 32 + kq0];
            b1 = *(const float4*)&Wih[(size_t)(col0 + c1) * NB_NINP + kb + 32 + kq1];
            b2 = *(const float4*)&Wih[(size_t)(col0 + c2) * NB_NINP + kb + 32 + kq2];
        }
        #pragma unroll
        for (int kk = 0; kk < 32; ++kk) {
            const float2 av = *(const float2*)&As[kk][rg * 2];
            const float2 w0 = *(const float2*)&Bs[kk][wc0];
            const float2 w1 = *(const float2*)&Bs[kk][wc0 + 2];
            const float2 w2 = *(const float2*)&Bs[kk][wc0 + 4];
            const float avv[2] = {av.x, av.y};
            const float wvv[6] = {w0.x, w0.y, w1.x, w1.y, w2.x, w2.y};
            #pragma unroll
            for (int i = 0; i < 2; ++i)
                #pragma unroll
                for (int e = 0; e < 6; ++e)
                    acc[i][e] = fmaf(avv[i], wvv[e], acc[i][e]);
        }
    }

    float bias[6];
    #pragma unroll
    for (int e = 0; e < 6; ++e) {
        const int cl = wc0 + e;           // c % 96
        const int c  = col0 + cl;
        bias[e] = bih[c] + (cl < 64 ? bhh[c] : 0.f);
    }
    #pragma unroll
    for (int i = 0; i < 2; ++i) {
        const size_t base = (size_t)(row0 + rg * 2 + i) * NB_C + col0 + wc0;
        #pragma unroll
        for (int e = 0; e < 6; e += 2) {
            float2 o; o.x = acc[i][e] + bias[e]; o.y = acc[i][e+1] + bias[e+1];
            *(float2*)&gi[base + e] = o;
        }
    }
}

// ---------------------------------------------------------------------------
// Kernel 2: fused gh-GEMM + GRU + write-key logits + gumbel-argmax + gather.
// 256 blocks x 1024 threads (16 waves = 4 waves/SIMD sharing one 96KB Whh).
// amdgpu_waves_per_eu(4,4) pins min AND max waves/EU -> VGPR budget exactly
// 128. (__launch_bounds__(1024,4) only sets the MIN; rounds 2/3 showed the
// compiler then picks 8/EU = 64 VGPR and spills ~1KB/thread = 250MB HBM.)
// Wave (bl,kh): b = blockIdx*8+bl, k-half kh; 2 passes of 4 k's, acc[4][12].
// P planes XOR-swizzled by (mm&7) (round-3: conflicts 6.9M -> 1.4M).
// ---------------------------------------------------------------------------
__global__ __launch_bounds__(1024)
__attribute__((amdgpu_waves_per_eu(4, 4)))
void k2_fused(const float* __restrict__ h,      const float* __restrict__ Whh,
              const float* __restrict__ bhh,    const float* __restrict__ wread,
              const float* __restrict__ wwrite, const float* __restrict__ gumb,
              const float* __restrict__ gi,     float* __restrict__ out)
{
    __shared__ __align__(16) float4 P[3][32][64];   // 98304 B  W_hh planes
    __shared__ float WWT[NB_T * 16 * 32];           // 16384 B  [t][f][m]
    __shared__ __align__(16) float WR[512];         //  2048 B  [m][f]
    __shared__ __align__(16) float HT[8][32][20];   // 20480 B  [bl][m][k]
    __shared__ __align__(16) float HR2T[8][16][20]; // 10240 B  [bl][f][k]

    const int tid  = threadIdx.x;
    const int wave = tid >> 6, lane = tid & 63;
    const int bl   = wave >> 1, kh = wave & 1;
    const int b    = blockIdx.x * 8 + bl;
    const int m_   = lane & 31, half = lane >> 5;

    // ---- stage W_hh planes (value for reading-lane sl at contraction mm
    //      lands at float4 slot sl ^ (mm&7) of row [j>>2][mm])
    float* PF = (float*)P;
    for (int i = tid; i < 24576; i += 1024) {       // Whh flat [c][m]; c=t*96+gc*32+mout
        const int c = i >> 5, mm = i & 31;
        const int t = c / 96, rem = c - t * 96;
        const int gc = rem >> 5, mout = rem & 31;
        const int j  = (t >> 1) * 3 + gc;
        const int sl = ((t & 1) * 32 + mout) ^ (mm & 7);
        PF[(((j >> 2) * 32 + mm) * 64 + sl) * 4 + (j & 3)] = Whh[i];
    }
    for (int i = tid; i < 4096; i += 1024) {        // wwrite flat [t][m][f]
        const int t = i >> 9, mo = (i >> 4) & 31, f = i & 15;
        WWT[t * 512 + f * 32 + mo] = wwrite[i];
    }
    if (tid < 512) WR[tid] = wread[tid];
    #pragma unroll
    for (int e = 0; e < 4; ++e) {                   // this wave's h half-row, transposed
        const int idx = kh * 256 + e * 64 + lane;
        HT[bl][idx & 31][idx >> 5] = h[(size_t)b * NB_NHID + idx];
    }
    __syncthreads();   // only barrier; everything below is wave-local

    // ---- h_read for this wave's 8 k's: lane owns (k = kh*8 + lane>>3, f-pair)
    {
        const int kq = kh * 8 + (lane >> 3);
        const int f0 = (lane & 7) * 2;
        float s0 = 0.f, s1 = 0.f;
        #pragma unroll 8
        for (int mm = 0; mm < 32; ++mm) {
            const float hv = HT[bl][mm][kq];
            s0 = fmaf(hv, WR[mm * 16 + f0], s0);
            s1 = fmaf(hv, WR[mm * 16 + f0 + 1], s1);
        }
        HR2T[bl][f0    ][kq] = s0;
        HR2T[bl][f0 + 1][kq] = s1;
    }

    // ---- per-lane gi' (bih+bhh_{r,z} folded by k1) and bhh_n
    float gi_r[4][3], bhn[4];
    #pragma unroll
    for (int p = 0; p < 4; ++p) {
        const int t = 2 * p + half;
        #pragma unroll
        for (int gc = 0; gc < 3; ++gc)
            gi_r[p][gc] = gi[(size_t)b * NB_C + t * 96 + gc * 32 + m_];
        bhn[p] = bhh[t * 96 + 64 + m_];
    }

    #pragma unroll 1
    for (int pass = 0; pass < 2; ++pass) {
        const int k0 = kh * 8 + pass * 4;

        // ---- gh GEMM, 4 k's: 48 FMA per mm; 3 spread b128 + 1 broadcast b128
        float acc[4][12];
        #pragma unroll
        for (int r = 0; r < 4; ++r)
            #pragma unroll
            for (int j = 0; j < 12; ++j) acc[r][j] = 0.f;

        #pragma unroll 4
        for (int mm = 0; mm < 32; ++mm) {
            const int sw = lane ^ (mm & 7);          // undo staging swizzle
            const float4 w0 = P[0][mm][sw];
            const float4 w1 = P[1][mm][sw];
            const float4 w2 = P[2][mm][sw];
            const float4 hv = *(const float4*)&HT[bl][mm][k0];   // broadcast
            const float wj[12] = {w0.x,w0.y,w0.z,w0.w, w1.x,w1.y,w1.z,w1.w,
                                  w2.x,w2.y,w2.z,w2.w};
            const float hr4[4] = {hv.x, hv.y, hv.z, hv.w};
            #pragma unroll
            for (int r = 0; r < 4; ++r)
                #pragma unroll
                for (int j = 0; j < 12; ++j)
                    acc[r][j] = fmaf(hr4[r], wj[j], acc[r][j]);
        }

        // ---- write-key dot ww[r][p] = sum_f w_write[t][m_][f] * h_read[k][f]
        float ww[4][4];
        #pragma unroll
        for (int r = 0; r < 4; ++r)
            #pragma unroll
            for (int p = 0; p < 4; ++p) ww[r][p] = 0.f;
        #pragma unroll 4
        for (int f = 0; f < 16; ++f) {
            float wt[4];
            #pragma unroll
            for (int p = 0; p < 4; ++p)
                wt[p] = WWT[(2 * p + half) * 512 + f * 32 + m_];
            const float4 hka = *(const float4*)&HR2T[bl][f][k0];  // broadcast
            const float hk[4] = {hka.x, hka.y, hka.z, hka.w};
            #pragma unroll
            for (int r = 0; r < 4; ++r)
                #pragma unroll
                for (int p = 0; p < 4; ++p)
                    ww[r][p] = fmaf(hk[r], wt[p], ww[r][p]);
        }

        // ---- per-k epilogue: gates, logits, argmax, gather
        #pragma unroll
        for (int r = 0; r < 4; ++r) {
            const int k = k0 + r;
            const float h2v = HT[bl][m_][k];
            float hn[4], lg[4];
            #pragma unroll
            for (int p = 0; p < 4; ++p) {
                const float xr = gi_r[p][0] + acc[r][p*3+0];
                const float xz = gi_r[p][1] + acc[r][p*3+1];
                const float gn = bhn[p]     + acc[r][p*3+2];
                const float rg = 1.f / (1.f + __expf(-xr));
                const float zg = 1.f / (1.f + __expf(-xz));
                const float xn = gi_r[p][2] + rg * gn;
                const float e2 = __expf(2.f * xn);
                const float tn = 1.f - 2.f / (e2 + 1.f);   // tanh
                const float hv2 = (1.f - zg) * tn + zg * h2v;
                hn[p] = hv2;
                float part = hv2 * ww[r][p];               // logit partial
                part += __shfl_xor(part, 1, 64);
                part += __shfl_xor(part, 2, 64);
                part += __shfl_xor(part, 4, 64);
                part += __shfl_xor(part, 8, 64);
                part += __shfl_xor(part, 16, 64);
                lg[p] = part;
            }
            float s[8];
            #pragma unroll
            for (int p = 0; p < 4; ++p) {
                const float oth = __shfl_xor(lg[p], 32, 64);
                s[2*p]   = half ? oth   : lg[p];
                s[2*p+1] = half ? lg[p] : oth;
            }
            const float* gp = gumb + ((size_t)b * NB_K + k) * NB_T;
            const float4 ga = *(const float4*)gp;
            const float4 gb = *(const float4*)(gp + 4);
            const float gv[8] = {ga.x,ga.y,ga.z,ga.w, gb.x,gb.y,gb.z,gb.w};
            float best = s[0] + gv[0]; int bt = 0;
            #pragma unroll
            for (int t2 = 1; t2 < 8; ++t2) {
                const float v = s[t2] + gv[t2];
                if (v > best) { best = v; bt = t2; }   // first-max argmax
            }
            const int pstar = bt >> 1, hstar = bt & 1;
            float hsel = hn[0];
            hsel = (pstar == 1) ? hn[1] : hsel;
            hsel = (pstar == 2) ? hn[2] : hsel;
            hsel = (pstar == 3) ? hn[3] : hsel;
            if (half == hstar)
                out[(size_t)b * NB_NHID + k * 32 + m_] = hsel;
            if (lane < 8)
                out[H_OUT_ELEMS + ((size_t)b * NB_K + k) * NB_T + lane] =
                    (lane == bt) ? 1.f : 0.f;
        }
    }
}

extern "C" void kernel_launch(void* const* d_in, const int* in_sizes, int n_in,
                              void* d_out, int out_size, void* d_ws, size_t ws_size,
                              hipStream_t stream) {
    const float* x      = (const float*)d_in[0];
    const float* h      = (const float*)d_in[1];
    const float* Wih    = (const float*)d_in[2];
    const float* Whh    = (const float*)d_in[3];
    const float* bih    = (const float*)d_in[4];
    const float* bhh    = (const float*)d_in[5];
    const float* wread  = (const float*)d_in[6];
    const float* wwrite = (const float*)d_in[7];
    const float* gumb   = (const float*)d_in[8];
    float* out = (float*)d_out;
    float* gi  = (float*)d_ws;   // 2048*768*4 = 6 MB scratch

    k1_gemm_gi<<<dim3(64, 8), 256, 0, stream>>>(x, Wih, bih, bhh, gi);
    k2_fused<<<dim3(256), 1024, 0, stream>>>(h, Whh, bhh, wread, wwrite,
                                             gumb, gi, out);
}